// Round 5
// baseline (425.945 us; speedup 1.0000x reference)
//
#include <hip/hip_runtime.h>
#include <hip/hip_bf16.h>

#define D 128

typedef __bf16 bf16x8 __attribute__((ext_vector_type(8)));
typedef __bf16 bf16x4 __attribute__((ext_vector_type(4)));
typedef __bf16 bf16x2 __attribute__((ext_vector_type(2)));
typedef float  f32x4  __attribute__((ext_vector_type(4)));
typedef float  f32x2  __attribute__((ext_vector_type(2)));

// ---------------------------------------------------------------------------
// Dtype probe: 1 = bf16-packed, 0 = fp32. (Kept as cheap insurance; R3/R4
// evidence says bf16: gemm FETCH == 4 x inp-as-bf16, WRITE == T-as-bf16.)
// ---------------------------------------------------------------------------
__global__ void detect_kernel(const unsigned int* __restrict__ w, int* flag)
{
    __shared__ int cnt[256];
    int c = 0;
#pragma unroll
    for (int i = 0; i < 4; ++i) {
        unsigned int v = w[threadIdx.x * 4 + i];
        unsigned int e = (v >> 7) & 0xFF;
        if (e >= 90 && e <= 134) ++c;
    }
    cnt[threadIdx.x] = c;
    __syncthreads();
    for (int s = 128; s > 0; s >>= 1) {
        if (threadIdx.x < s) cnt[threadIdx.x] += cnt[threadIdx.x + s];
        __syncthreads();
    }
    if (threadIdx.x == 0) flag[0] = (cnt[0] > 614) ? 1 : 0;
}

template <int ISBF>
__device__ __forceinline__ bf16x8 ld8(const void* p, size_t elem)
{
    if (ISBF) return *(const bf16x8*)((const __bf16*)p + elem);
    const f32x4* f = (const f32x4*)((const float*)p + elem);
    f32x4 lo = f[0], hi = f[1];
    bf16x8 r;
    r[0] = (__bf16)lo[0]; r[1] = (__bf16)lo[1]; r[2] = (__bf16)lo[2]; r[3] = (__bf16)lo[3];
    r[4] = (__bf16)hi[0]; r[5] = (__bf16)hi[1]; r[6] = (__bf16)hi[2]; r[7] = (__bf16)hi[3];
    return r;
}
template <int ISBF>
__device__ __forceinline__ f32x2 ld2f(const void* p, size_t elem)
{
    f32x2 r;
    if (ISBF) {
        bf16x2 v = *(const bf16x2*)((const __bf16*)p + elem);
        r[0] = (float)v[0]; r[1] = (float)v[1];
    } else {
        r = *(const f32x2*)((const float*)p + elem);
    }
    return r;
}
template <int ISBF>
__device__ __forceinline__ float ldf(const void* p, size_t elem)
{
    return ISBF ? (float)((const __bf16*)p)[elem] : ((const float*)p)[elem];
}

// ---------------------------------------------------------------------------
// Phase 1 (fused): T[t][n][:] = inp[n][:] @ W_t^T for all 4 t in one block.
// inp fragments loaded ONCE into registers (A fetched 1x, not 4x).
// Transposed-operand MFMA: A-op = W rows (features), B-op = inp rows (nodes)
// -> lane's 4 acc regs = 4 consecutive features of one node -> 8B stores.
// ---------------------------------------------------------------------------
template <int ISBF>
__device__ __forceinline__ void gemm_body(
    const void* __restrict__ A,
    const void* __restrict__ W0, const void* __restrict__ W1,
    const void* __restrict__ W2, const void* __restrict__ W3,
    __bf16* __restrict__ T, int M)
{
    const int wave = threadIdx.x >> 6;
    const int lane = threadIdx.x & 63;
    const int lrow = lane & 15;   // node-in-tile (B-op n) / W-row-in-tile (A-op m)
    const int kgrp = lane >> 4;   // k subgroup
    const int m_base = blockIdx.x * 128 + wave * 32;

    int n0 = m_base + lrow;      if (n0 >= M) n0 = 0;   // clamped; stores guarded
    int n1 = m_base + 16 + lrow; if (n1 >= M) n1 = 0;

    // inp fragments: af[nt][ks], lane holds inp[node][ks*32+kgrp*8 .. +8]
    bf16x8 af[2][4];
#pragma unroll
    for (int ks = 0; ks < 4; ++ks) {
        const int k0 = ks * 32 + kgrp * 8;
        af[0][ks] = ld8<ISBF>(A, (size_t)n0 * D + k0);
        af[1][ks] = ld8<ISBF>(A, (size_t)n1 * D + k0);
    }

    const void* Ws[4] = {W0, W1, W2, W3};
#pragma unroll
    for (int t = 0; t < 4; ++t) {
        const void* W = Ws[t];
        f32x4 acc[2][8];
#pragma unroll
        for (int i = 0; i < 2; ++i)
#pragma unroll
            for (int j = 0; j < 8; ++j)
                acc[i][j] = (f32x4){0.f, 0.f, 0.f, 0.f};

#pragma unroll
        for (int ks = 0; ks < 4; ++ks) {
            const int k0 = ks * 32 + kgrp * 8;
#pragma unroll
            for (int ft = 0; ft < 8; ++ft) {
                bf16x8 wf = ld8<ISBF>(W, (size_t)(ft * 16 + lrow) * D + k0);
                // D[m=feature][n=node]
                acc[0][ft] = __builtin_amdgcn_mfma_f32_16x16x32_bf16(wf, af[0][ks], acc[0][ft], 0, 0, 0);
                acc[1][ft] = __builtin_amdgcn_mfma_f32_16x16x32_bf16(wf, af[1][ks], acc[1][ft], 0, 0, 0);
            }
        }

        // lane's node: m_base + nt*16 + lrow; features ft*16 + kgrp*4 + {0..3}
        __bf16* Tt = T + (size_t)t * M * D;
#pragma unroll
        for (int nt = 0; nt < 2; ++nt) {
            int node = m_base + nt * 16 + lrow;
            if (node < M) {
#pragma unroll
                for (int ft = 0; ft < 8; ++ft) {
                    bf16x4 w4;
                    w4[0] = (__bf16)acc[nt][ft][0];
                    w4[1] = (__bf16)acc[nt][ft][1];
                    w4[2] = (__bf16)acc[nt][ft][2];
                    w4[3] = (__bf16)acc[nt][ft][3];
                    *(bf16x4*)(Tt + (size_t)node * D + ft * 16 + kgrp * 4) = w4;
                }
            }
        }
    }
}

__global__ __launch_bounds__(256) void gemm_kernel(
    const void* __restrict__ A,
    const void* __restrict__ W0, const void* __restrict__ W1,
    const void* __restrict__ W2, const void* __restrict__ W3,
    __bf16* __restrict__ T, int M, const int* __restrict__ flag)
{
    if (flag[0]) gemm_body<1>(A, W0, W1, W2, W3, T, M);
    else         gemm_body<0>(A, W0, W1, W2, W3, T, M);
}

// ---------------------------------------------------------------------------
// Phase 1b: G[t][n] = dot(inp[n], gate_t), fp32. One wave per node.
// ---------------------------------------------------------------------------
template <int ISBF>
__device__ __forceinline__ void gate_body(
    const void* __restrict__ A,
    const void* __restrict__ g0, const void* __restrict__ g1,
    const void* __restrict__ g2, const void* __restrict__ g3,
    float* __restrict__ G, int M)
{
    int node = blockIdx.x * 4 + (threadIdx.x >> 6);
    int lane = threadIdx.x & 63;
    if (node >= M) return;
    int d = lane * 2;
    f32x2 a  = ld2f<ISBF>(A, (size_t)node * D + d);
    f32x2 v0 = ld2f<ISBF>(g0, d);
    f32x2 v1 = ld2f<ISBF>(g1, d);
    f32x2 v2 = ld2f<ISBF>(g2, d);
    f32x2 v3 = ld2f<ISBF>(g3, d);
    float s0 = a[0] * v0[0] + a[1] * v0[1];
    float s1 = a[0] * v1[0] + a[1] * v1[1];
    float s2 = a[0] * v2[0] + a[1] * v2[1];
    float s3 = a[0] * v3[0] + a[1] * v3[1];
#pragma unroll
    for (int off = 32; off > 0; off >>= 1) {
        s0 += __shfl_down(s0, off);
        s1 += __shfl_down(s1, off);
        s2 += __shfl_down(s2, off);
        s3 += __shfl_down(s3, off);
    }
    if (lane == 0) {
        G[(size_t)0 * M + node] = s0;
        G[(size_t)1 * M + node] = s1;
        G[(size_t)2 * M + node] = s2;
        G[(size_t)3 * M + node] = s3;
    }
}

__global__ __launch_bounds__(256) void gate_kernel(
    const void* __restrict__ A,
    const void* __restrict__ g0, const void* __restrict__ g1,
    const void* __restrict__ g2, const void* __restrict__ g3,
    float* __restrict__ G, int M, const int* __restrict__ flag)
{
    if (flag[0]) gate_body<1>(A, g0, g1, g2, g3, G, M);
    else         gate_body<0>(A, g0, g1, g2, g3, G, M);
}

// ---------------------------------------------------------------------------
// CSR build: histogram -> scan -> scatter (counting sort by target node)
// ---------------------------------------------------------------------------
__global__ __launch_bounds__(256) void hist_kernel(
    const int* __restrict__ tgt, int* __restrict__ counts, int E)
{
    int e = blockIdx.x * 256 + threadIdx.x;
    if (e < E) atomicAdd(&counts[tgt[e]], 1);
}

__global__ __launch_bounds__(256) void scan1_kernel(
    const int* __restrict__ counts, int* __restrict__ rowptr,
    int* __restrict__ bsum, int M)
{
    __shared__ int sh[256];
    int base = blockIdx.x * 1024 + threadIdx.x * 4;
    int v[4];
#pragma unroll
    for (int k = 0; k < 4; ++k)
        v[k] = (base + k < M) ? counts[base + k] : 0;
    int tot = v[0] + v[1] + v[2] + v[3];
    sh[threadIdx.x] = tot;
    __syncthreads();
    for (int off = 1; off < 256; off <<= 1) {
        int t = (threadIdx.x >= off) ? sh[threadIdx.x - off] : 0;
        __syncthreads();
        sh[threadIdx.x] += t;
        __syncthreads();
    }
    int run = sh[threadIdx.x] - tot;
#pragma unroll
    for (int k = 0; k < 4; ++k) {
        if (base + k < M) rowptr[base + k] = run;
        run += v[k];
    }
    if (threadIdx.x == 255) bsum[blockIdx.x] = sh[255];
}

__global__ __launch_bounds__(256) void scan2_kernel(
    int* __restrict__ bsum, int* __restrict__ boff, int NB)
{
    __shared__ int sh[256];
    int base = threadIdx.x * 4;
    int v[4];
#pragma unroll
    for (int k = 0; k < 4; ++k)
        v[k] = (base + k < NB) ? bsum[base + k] : 0;
    int tot = v[0] + v[1] + v[2] + v[3];
    sh[threadIdx.x] = tot;
    __syncthreads();
    for (int off = 1; off < 256; off <<= 1) {
        int t = (threadIdx.x >= off) ? sh[threadIdx.x - off] : 0;
        __syncthreads();
        sh[threadIdx.x] += t;
        __syncthreads();
    }
    int run = sh[threadIdx.x] - tot;
#pragma unroll
    for (int k = 0; k < 4; ++k) {
        if (base + k < NB) boff[base + k] = run;
        run += v[k];
    }
}

__global__ __launch_bounds__(256) void scan3_kernel(
    int* __restrict__ rowptr, int* __restrict__ cursor,
    const int* __restrict__ boff, int M, int E)
{
    int b = blockIdx.x;
    int base = b * 1024 + threadIdx.x * 4;
    int o = boff[b];
#pragma unroll
    for (int k = 0; k < 4; ++k) {
        int i = base + k;
        if (i < M) {
            int r = rowptr[i] + o;
            rowptr[i] = r;
            cursor[i] = r;
        }
    }
    if (b == 0 && threadIdx.x == 0) rowptr[M] = E;
}

__global__ __launch_bounds__(256) void scatter_kernel(
    const int* __restrict__ deprel, const int* __restrict__ deparc,
    const int* __restrict__ src, const int* __restrict__ tgt,
    int* __restrict__ cursor, int2* __restrict__ recs, int E)
{
    int e = blockIdx.x * 256 + threadIdx.x;
    if (e >= E) return;
    int g = tgt[e];
    int pos = atomicAdd(&cursor[g], 1);
    recs[pos] = make_int2(src[e], (deprel[e] << 2) | deparc[e]);
}

// ---------------------------------------------------------------------------
// Phase 2: atomic-free gather. One wave per target node.
// ---------------------------------------------------------------------------
template <int ISBF>
__device__ __forceinline__ void gather_body(
    const __bf16* __restrict__ T, const float* __restrict__ G,
    const void* __restrict__ b_in, const void* __restrict__ b_out,
    const void* __restrict__ bg_in, const void* __restrict__ bg_out,
    const int* __restrict__ rowptr, const int2* __restrict__ recs,
    void* __restrict__ out, int M)
{
    int g = blockIdx.x * 4 + (threadIdx.x >> 6);
    if (g >= M) return;
    int lane = threadIdx.x & 63;
    int beg = rowptr[g], end = rowptr[g + 1];

    float a0 = 0.f, a1 = 0.f;
    int d = lane * 2;
    for (int base = beg; base < end; base += 64) {
        int n = end - base; if (n > 64) n = 64;
        int2 rec = (lane < n) ? recs[base + lane] : make_int2(0, 0);
        int t = rec.y & 3, r = rec.y >> 2;
        float gpre = G[(size_t)t * M + rec.x];
        float bg = 0.f;
        if (t == 0)      bg = ldf<ISBF>(bg_in, r);
        else if (t == 1) bg = ldf<ISBF>(bg_out, r);
        float gate = 1.f / (1.f + __expf(-(gpre + bg)));

        for (int j = 0; j < n; ++j) {
            int sj = __shfl(rec.x, j);
            int mj = __shfl(rec.y, j);
            float gj = __shfl(gate, j);
            int tj = mj & 3, rj = mj >> 2;   // wave-uniform after shuffle
            bf16x2 tv = *(const bf16x2*)(T + ((size_t)tj * M + sj) * D + d);
            float m0 = (float)tv[0], m1 = (float)tv[1];
            if (tj == 0) {
                f32x2 bv = ld2f<ISBF>(b_in, (size_t)rj * D + d);
                m0 += bv[0]; m1 += bv[1];
            } else if (tj == 1) {
                f32x2 bv = ld2f<ISBF>(b_out, (size_t)rj * D + d);
                m0 += bv[0]; m1 += bv[1];
            }
            a0 += m0 * gj;
            a1 += m1 * gj;
        }
    }

    if (ISBF) {
        bf16x2 w; w[0] = (__bf16)a0; w[1] = (__bf16)a1;
        *(bf16x2*)((__bf16*)out + (size_t)g * D + d) = w;
    } else {
        f32x2 w; w[0] = a0; w[1] = a1;
        *(f32x2*)((float*)out + (size_t)g * D + d) = w;
    }
}

__global__ __launch_bounds__(256) void gather_kernel(
    const __bf16* __restrict__ T, const float* __restrict__ G,
    const void* __restrict__ b_in, const void* __restrict__ b_out,
    const void* __restrict__ bg_in, const void* __restrict__ bg_out,
    const int* __restrict__ rowptr, const int2* __restrict__ recs,
    void* __restrict__ out, int M, const int* __restrict__ flag)
{
    if (flag[0]) gather_body<1>(T, G, b_in, b_out, bg_in, bg_out, rowptr, recs, out, M);
    else         gather_body<0>(T, G, b_in, b_out, bg_in, bg_out, rowptr, recs, out, M);
}

__global__ void sentinel_kernel(__bf16* o, int n)
{
    int i = blockIdx.x * blockDim.x + threadIdx.x;
    if (i < n) o[i] = (__bf16)12345.0f;
}

static inline size_t align256(size_t x) { return (x + 255) & ~(size_t)255; }

extern "C" void kernel_launch(void* const* d_in, const int* in_sizes, int n_in,
                              void* d_out, int out_size, void* d_ws, size_t ws_size,
                              hipStream_t stream)
{
    const void* inp       = d_in[0];
    const int*  deprel    = (const int*)d_in[1];
    const int*  deparc    = (const int*)d_in[2];
    const int*  eidx      = (const int*)d_in[3];
    const void* V_in      = d_in[4];
    const void* b_in      = d_in[5];
    const void* V_in_g    = d_in[6];
    const void* b_in_g    = d_in[7];
    const void* V_out     = d_in[8];
    const void* b_out     = d_in[9];
    const void* V_out_g   = d_in[10];
    const void* b_out_g   = d_in[11];
    const void* W_self    = d_in[12];
    const void* W_self_g  = d_in[13];
    const void* W_norel   = d_in[14];
    const void* W_norel_g = d_in[15];

    const int M = in_sizes[0] / D;   // 100000
    const int E = in_sizes[1];       // 600000
    const int* src = eidx;
    const int* tgt = eidx + E;
    const int NB = (M + 1023) / 1024;

    size_t off = 0;
    size_t o_flag   = off; off = align256(off + sizeof(int));
    size_t o_T      = off; off = align256(off + (size_t)4 * M * D * sizeof(__bf16));
    size_t o_G      = off; off = align256(off + (size_t)4 * M * sizeof(float));
    size_t o_counts = off; off = align256(off + (size_t)M * sizeof(int));
    size_t o_rowptr = off; off = align256(off + (size_t)(M + 1) * sizeof(int));
    size_t o_cursor = off; off = align256(off + (size_t)M * sizeof(int));
    size_t o_bsum   = off; off = align256(off + (size_t)NB * sizeof(int));
    size_t o_boff   = off; off = align256(off + (size_t)NB * sizeof(int));
    size_t o_recs   = off; off = align256(off + (size_t)E * sizeof(int2));

    if (off > ws_size) {
        sentinel_kernel<<<(out_size + 255) / 256, 256, 0, stream>>>(
            (__bf16*)d_out, out_size);
        return;
    }

    int*    flag   = (int*)((char*)d_ws + o_flag);
    __bf16* Tbuf   = (__bf16*)((char*)d_ws + o_T);
    float*  Gbuf   = (float*)((char*)d_ws + o_G);
    int*    counts = (int*)((char*)d_ws + o_counts);
    int*    rowptr = (int*)((char*)d_ws + o_rowptr);
    int*    cursor = (int*)((char*)d_ws + o_cursor);
    int*    bsum   = (int*)((char*)d_ws + o_bsum);
    int*    boff   = (int*)((char*)d_ws + o_boff);
    int2*   recs   = (int2*)((char*)d_ws + o_recs);

    detect_kernel<<<1, 256, 0, stream>>>((const unsigned int*)inp, flag);

    // CSR build (independent of gemm/gate)
    hipMemsetAsync(counts, 0, (size_t)M * sizeof(int), stream);
    hist_kernel<<<(E + 255) / 256, 256, 0, stream>>>(tgt, counts, E);
    scan1_kernel<<<NB, 256, 0, stream>>>(counts, rowptr, bsum, M);
    scan2_kernel<<<1, 256, 0, stream>>>(bsum, boff, NB);
    scan3_kernel<<<NB, 256, 0, stream>>>(rowptr, cursor, boff, M, E);
    scatter_kernel<<<(E + 255) / 256, 256, 0, stream>>>(deprel, deparc, src, tgt,
                                                        cursor, recs, E);

    // node transforms + gates (gemm now fused over t: inp fetched once)
    gemm_kernel<<<(M + 127) / 128, 256, 0, stream>>>(inp, V_in, V_out, W_self,
                                                     W_norel, Tbuf, M, flag);
    gate_kernel<<<(M + 3) / 4, 256, 0, stream>>>(inp, V_in_g, V_out_g, W_self_g,
                                                 W_norel_g, Gbuf, M, flag);

    gather_kernel<<<(M + 3) / 4, 256, 0, stream>>>(Tbuf, Gbuf, b_in, b_out,
                                                   b_in_g, b_out_g,
                                                   rowptr, recs, d_out, M, flag);
}